// Round 7
// baseline (219.555 us; speedup 1.0000x reference)
//
#include <hip/hip_runtime.h>
#include <hip/hip_bf16.h>
#include <stdint.h>

// ---------------------------------------------------------------------------
// CustomConvLayer: out[b,o,h,w] = sum_{c,dh,dw} xpad[b,c,h+dh,w+dw] * W[o,c,dh*3+dw]
// Implicit-im2col GEMM, bf16 MFMA 16x16x32. M=B*H*W, N=128, K=576.
//
// R10 = R8 resubmitted verbatim (R8/R9 benches died to infra before running;
// OOB/hang/alignment audit found nothing kernel-side -- see session notes).
// Rationale recap: R4/R6/R7 scheduling variants all land at conv ~62-65us
// (scheduling is not the lever); the invariant costs are the xpad round-trip
// (69MB + a 22us kernel) and the mixed R/W HBM stream. R5's fused attempt
// failed because its transpose was 12 barrier-serialized units with scalar
// u16 LDS GATHERS (786K conflict cycles). Here the transpose needs NO extra
// barriers and NO LDS gather: each thread owns one (c-octet,w) column, loads
// 8 coalesced scalar dwords per unit (lanes along w -> 2x128B segments per
// instr), converts in-register, writes ONE 16B swizzled chunk directly into
// Aslab (depth-4 load ring, constant-indexed). One __syncthreads(), then the
// R3/R5-verbatim 18-step barrier-free MFMA loop (BtF via direct register
// loads -- proven) and the proven epilogue.
// Deleted: xform_x kernel, 34.6MB xpad write, 34.6MB scattered xpad read.
// LDS = 49,920B -> 3 blocks/CU.
// ---------------------------------------------------------------------------

typedef __bf16 bf16x8 __attribute__((ext_vector_type(8)));
typedef float  f32x4  __attribute__((ext_vector_type(4)));

// ---------------- weights -> fragment-order BtF[s][quad][n] 16B chunks -------
// chunk(s,quad,n)[r] = W[n][c][tap] with k = s*32+quad*8+r, tap=k>>6, c=k&63
__global__ __launch_bounds__(256) void xform_w(const float* __restrict__ wgt,
                                               __bf16* __restrict__ BtF) {
  const int t = blockIdx.x * 256 + threadIdx.x;  // chunk id
  if (t >= 9216) return;
  const int s = t >> 9, rem = t & 511, quad = rem >> 7, n = rem & 127;
  bf16x8 o;
#pragma unroll
  for (int r = 0; r < 8; ++r) {
    const int k = s * 32 + quad * 8 + r;
    const int tap = k >> 6, c = k & 63;
    o[r] = (__bf16)wgt[(n * 64 + c) * 9 + tap];
  }
  *(bf16x8*)(BtF + (size_t)t * 8) = o;
}

// ---------------- fused conv: block=(b,h); in-register NCHW->slab transpose --
__global__ __launch_bounds__(256) void conv_mfma(const float* __restrict__ x,
                                                 const __bf16* __restrict__ BtF,
                                                 float* __restrict__ out) {
  __shared__ alignas(16) __bf16 Aslab[3120 * 8];  // 49,920 B: 3 rows x 130 wp x 64 c
  const int tid  = threadIdx.x;
  const int lane = tid & 63;
  const int wave = tid >> 6;
  const int quad = lane >> 4;
  const int l16  = lane & 15;
  // XCD-aware swizzle: same-XCD blocks get contiguous (b,h) -> x-row L2 reuse
  const int rank = (blockIdx.x & 7) * 256 + (blockIdx.x >> 3);
  const int b = rank >> 7;
  const int h = rank & 127;
  const int wm = wave >> 1;  // M half
  const int wn = wave & 1;   // N half

  // ---- edge chunks wp=0 / wp=129 -> zeros (48 chunks; ordered by the barrier)
  if (tid < 48) {
    const int r3 = tid >> 4, wp = ((tid >> 3) & 1) * 129, cq = tid & 7;
    const int v = r3 * 130 + wp;
    const bf16x8 z = {};
    *(bf16x8*)(Aslab + (size_t)(v * 8 + (cq ^ (v & 7))) * 8) = z;
  }

  // ---- transpose staging: 12 units (u=t>>2 slab row, p=t&3 w-quarter).
  // Thread owns (c8 = tid>>5 c-octet, wl = tid&31). Per unit: 8 coalesced
  // scalar dword loads (lanes along w), cvt in reg, ONE 16B swizzled ds_write.
  const int c8 = tid >> 5;
  const int wl = tid & 31;
  const float* xb = x + ((size_t)b * 64 + c8 * 8) * 16384 + wl;  // + cc*16384 + xr*128 + p*32

  float f[4][8];  // depth-4 ring; constant-indexed under full unroll

#define T_ISSUE(T) do {                                                       \
    const int u_ = (T) >> 2, p_ = (T) & 3;                                    \
    const int xr_ = h - 1 + u_;                                               \
    if (xr_ >= 0 && xr_ <= 127) {                                             \
      const float* p0_ = xb + (size_t)xr_ * 128 + p_ * 32;                    \
      _Pragma("unroll")                                                       \
      for (int cc = 0; cc < 8; ++cc) f[(T) & 3][cc] = p0_[(size_t)cc * 16384];\
    }                                                                         \
  } while (0)

#define T_CONSUME(T) do {                                                     \
    const int u_ = (T) >> 2, p_ = (T) & 3;                                    \
    const int xr_ = h - 1 + u_;                                               \
    bf16x8 pk = {};                                                           \
    if (xr_ >= 0 && xr_ <= 127) {                                             \
      _Pragma("unroll")                                                       \
      for (int cc = 0; cc < 8; ++cc) pk[cc] = (__bf16)f[(T) & 3][cc];         \
    }                                                                         \
    const int v_ = u_ * 130 + 1 + p_ * 32 + wl;                               \
    *(bf16x8*)(Aslab + (size_t)(v_ * 8 + (c8 ^ (v_ & 7))) * 8) = pk;          \
  } while (0)

  T_ISSUE(0); T_ISSUE(1); T_ISSUE(2);
#pragma unroll
  for (int t = 0; t < 12; ++t) {
    if (t < 9) T_ISSUE(t + 3);   // ring slot (t+3)&3 != t&3: safe before consume
    T_CONSUME(t);
  }
  __syncthreads();  // the only barrier

  // ---- R3/R5-verbatim compute: 18 s-steps, no barriers ----
  f32x4 acc[4][4] = {};
#pragma unroll
  for (int s = 0; s < 18; ++s) {
    const int tap = s >> 1;
    const int dh = tap / 3, dw = tap % 3;
    const int cq = ((s & 1) << 2) + quad;  // 16B chunk index within a 64-elem row
    bf16x8 aF[4], bF[4];                   // plain locals, constant-indexed (SROA)
#pragma unroll
    for (int i = 0; i < 4; ++i) {
      const int m = (wm << 6) + (i << 4) + l16;
      const int v = dh * 130 + m + dw;
      const int slot = (v << 3) + (cq ^ (v & 7));
      aF[i] = *(const bf16x8*)(Aslab + (size_t)slot * 8);
      const int n = (wn << 6) + (i << 4) + l16;
      bF[i] = *(const bf16x8*)(BtF + ((size_t)((s * 4 + quad) * 128 + n) << 3));
    }
#pragma unroll
    for (int i = 0; i < 4; ++i)
#pragma unroll
      for (int j = 0; j < 4; ++j)
        acc[i][j] = __builtin_amdgcn_mfma_f32_16x16x32_bf16(aF[i], bF[j], acc[i][j], 0, 0, 0);
  }

  // epilogue: D col = lane&15 = n, row = quad*4+reg = m (out w). Plain stores.
#pragma unroll
  for (int j = 0; j < 4; ++j) {
    const int n = (wn << 6) + (j << 4) + l16;
    float* orow = out + (((size_t)(b * 128 + n) * 128 + h) << 7);
#pragma unroll
    for (int i = 0; i < 4; ++i) {
      const int m0 = (wm << 6) + (i << 4) + (quad << 2);
      *(f32x4*)(orow + m0) = acc[i][j];  // quads 0..3 tile one 64B line per n
    }
  }
}

// ---------------- fallback (if workspace too small): direct fp32 conv -------
__global__ void conv_naive(const float* __restrict__ x, const float* __restrict__ wgt,
                           float* __restrict__ out, int total) {
  int idx = blockIdx.x * 256 + threadIdx.x;
  if (idx >= total) return;
  const int w = idx & 127;
  const int h = (idx >> 7) & 127;
  const int o = (idx >> 14) & 127;
  const int b = idx >> 21;
  float s = 0.f;
  for (int c = 0; c < 64; ++c) {
    const float* xc = x + ((size_t)(b * 64 + c) * 128) * 128;
    const float* wc = wgt + (o * 64 + c) * 9;
    for (int dh = 0; dh < 3; ++dh) {
      const int hh = h + dh - 1;
      if (hh < 0 || hh >= 128) continue;
      for (int dw = 0; dw < 3; ++dw) {
        const int ww = w + dw - 1;
        if (ww < 0 || ww >= 128) continue;
        s += xc[hh * 128 + ww] * wc[dh * 3 + dw];
      }
    }
  }
  out[idx] = s;
}

extern "C" void kernel_launch(void* const* d_in, const int* in_sizes, int n_in,
                              void* d_out, int out_size, void* d_ws, size_t ws_size,
                              hipStream_t stream) {
  const float* x   = (const float*)d_in[0];
  const float* wgt = (const float*)d_in[1];
  float* out = (float*)d_out;

  const size_t BTF_BYTES = 9216ull * 16;  // 147456 (L2-resident)

  if (ws_size < BTF_BYTES) {
    const int total = 16 * 128 * 128 * 128;
    conv_naive<<<(total + 255) / 256, 256, 0, stream>>>(x, wgt, out, total);
    return;
  }

  __bf16* BtF = (__bf16*)d_ws;

  xform_w<<<36, 256, 0, stream>>>(wgt, BtF);
  conv_mfma<<<2048, 256, 0, stream>>>(x, BtF, out);
}